// Round 1
// baseline (80.574 us; speedup 1.0000x reference)
//
#include <hip/hip_runtime.h>

// SPLoPA adapter: out[r][c] = weights[r][c] + sum_k pos[k, r/32, c/32] * w[k, r%32] * h[k, c%32]
// weights: 2048x2048 f32; pos: (64,64,64) f32; proto_w: (64,32,1) f32; proto_h: (64,1,32) f32
//
// Layout: grid of 1024 blocks x 256 threads. Each block = 4 waves; each wave
// computes one 32x32 output tile (4096 tiles total). Each lane computes a 4x4
// micro-tile: a0 = (lane>>3)*4 rows, b0 = (lane&7)*4 cols -> stores are 8x128B
// contiguous segments per wave (fully coalesced).
// w,h (8 KB each) are staged once per block into LDS; k-loop reads are 8-way
// lane-broadcast ds_read_b128 (broadcast is free on gfx950).
// pos[k,i,j] is wave-uniform: readfirstlane(ij) forces s_load_dword per k.

#define KDIM 64

__global__ __launch_bounds__(256) void splopa_kernel(
    const float* __restrict__ weights,
    const float* __restrict__ pos,
    const float* __restrict__ pw,    // (64,32): w[k*32 + a]
    const float* __restrict__ ph,    // (64,32): h[k*32 + b]
    float* __restrict__ out)
{
    __shared__ float w_lds[KDIM * 32];
    __shared__ float h_lds[KDIM * 32];

    const int tid = threadIdx.x;  // 0..255

    // Stage w,h into LDS: 2048 floats = 512 float4 each; 256 threads x 2 iters.
    {
        const float4* wg = (const float4*)pw;
        const float4* hg = (const float4*)ph;
        float4* wl = (float4*)w_lds;
        float4* hl = (float4*)h_lds;
        wl[tid]       = wg[tid];
        wl[tid + 256] = wg[tid + 256];
        hl[tid]       = hg[tid];
        hl[tid + 256] = hg[tid + 256];
    }

    const int wave = tid >> 6;   // 0..3
    const int lane = tid & 63;

    const int t = (blockIdx.x << 2) + wave;  // tile id 0..4095
    const int i = t >> 6;                    // row tile
    const int j = t & 63;                    // col tile
    int ij = (i << 6) + j;
    ij = __builtin_amdgcn_readfirstlane(ij); // wave-uniform -> scalar loads of pos

    const int a0 = (lane >> 3) << 2;  // 0,4,...,28
    const int b0 = (lane & 7) << 2;   // 0,4,...,28

    const int row0 = (i << 5) + a0;
    const int col0 = (j << 5) + b0;
    const float* wptr = weights + (size_t)row0 * 2048 + col0;
    float*       optr = out     + (size_t)row0 * 2048 + col0;

    // Prefetch the 4x4 weights micro-tile early (overlaps the k-loop latency).
    float4 wt0 = *(const float4*)(wptr);
    float4 wt1 = *(const float4*)(wptr + 2048);
    float4 wt2 = *(const float4*)(wptr + 4096);
    float4 wt3 = *(const float4*)(wptr + 6144);

    float4 acc0 = {0.f, 0.f, 0.f, 0.f};
    float4 acc1 = {0.f, 0.f, 0.f, 0.f};
    float4 acc2 = {0.f, 0.f, 0.f, 0.f};
    float4 acc3 = {0.f, 0.f, 0.f, 0.f};

    __syncthreads();

    #pragma unroll
    for (int k = 0; k < KDIM; ++k) {
        const float  pk = pos[(k << 12) + ij];                 // s_load (uniform)
        const float4 wv = *(const float4*)&w_lds[(k << 5) + a0]; // ds_read_b128, 8-way bcast
        const float4 hv = *(const float4*)&h_lds[(k << 5) + b0]; // ds_read_b128, 8-way bcast

        const float t0 = pk * wv.x;
        const float t1 = pk * wv.y;
        const float t2 = pk * wv.z;
        const float t3 = pk * wv.w;

        acc0.x += t0 * hv.x; acc0.y += t0 * hv.y; acc0.z += t0 * hv.z; acc0.w += t0 * hv.w;
        acc1.x += t1 * hv.x; acc1.y += t1 * hv.y; acc1.z += t1 * hv.z; acc1.w += t1 * hv.w;
        acc2.x += t2 * hv.x; acc2.y += t2 * hv.y; acc2.z += t2 * hv.z; acc2.w += t2 * hv.w;
        acc3.x += t3 * hv.x; acc3.y += t3 * hv.y; acc3.z += t3 * hv.z; acc3.w += t3 * hv.w;
    }

    wt0.x += acc0.x; wt0.y += acc0.y; wt0.z += acc0.z; wt0.w += acc0.w;
    wt1.x += acc1.x; wt1.y += acc1.y; wt1.z += acc1.z; wt1.w += acc1.w;
    wt2.x += acc2.x; wt2.y += acc2.y; wt2.z += acc2.z; wt2.w += acc2.w;
    wt3.x += acc3.x; wt3.y += acc3.y; wt3.z += acc3.z; wt3.w += acc3.w;

    *(float4*)(optr)        = wt0;
    *(float4*)(optr + 2048) = wt1;
    *(float4*)(optr + 4096) = wt2;
    *(float4*)(optr + 6144) = wt3;
}

extern "C" void kernel_launch(void* const* d_in, const int* in_sizes, int n_in,
                              void* d_out, int out_size, void* d_ws, size_t ws_size,
                              hipStream_t stream) {
    const float* weights = (const float*)d_in[0];  // 2048*2048
    const float* pos     = (const float*)d_in[1];  // 64*64*64
    const float* pw      = (const float*)d_in[2];  // 64*32*1
    const float* ph      = (const float*)d_in[3];  // 64*1*32
    float* out = (float*)d_out;                    // 2048*2048

    splopa_kernel<<<1024, 256, 0, stream>>>(weights, pos, pw, ph, out);
}